// Round 4
// baseline (590.185 us; speedup 1.0000x reference)
//
#include <hip/hip_runtime.h>
#include <hip/hip_bf16.h>
#include <cstddef>
#include <cstdint>

#define LN_EPS 1e-5f

// Problem dims (fixed by the reference)
#define B_DIM 8192
#define D_DIM 4096
#define H_DIM 2048
#define K_DIM 512

typedef __bf16 bf16x8_t __attribute__((ext_vector_type(8)));
typedef float f32x4_t __attribute__((ext_vector_type(4)));

// ---------------------------------------------------------------------------
// async global->LDS, 16B per lane. LDS dest = wave-uniform base + lane*16.
// ---------------------------------------------------------------------------
__device__ __forceinline__ void gl2lds16(const __hip_bfloat16* g,
                                         __hip_bfloat16* l) {
  __builtin_amdgcn_global_load_lds(
      (const __attribute__((address_space(1))) uint32_t*)g,
      (__attribute__((address_space(3))) uint32_t*)l, 16, 0, 0);
}

// ---------------------------------------------------------------------------
// f32 -> bf16 pre-convert, ONE launch: x-cmean (16384 blks), W1 (4096),
// W2 (512), beta (1024). 2048 f32 per block.
// ---------------------------------------------------------------------------
__global__ __launch_bounds__(256) void conv_all_kernel(
    const float* __restrict__ x, const float* __restrict__ cmean,
    __hip_bfloat16* __restrict__ xb, const float* __restrict__ W1,
    const float* __restrict__ W2, const float* __restrict__ beta,
    __hip_bfloat16* __restrict__ W1b, __hip_bfloat16* __restrict__ W2b,
    __hip_bfloat16* __restrict__ betab) {
  const int blk = blockIdx.x;
  if (blk < 16384) {  // x - cmean
    const long i = (((long)blk << 8) + threadIdx.x) << 3;
    const int col = (int)(i & (D_DIM - 1));
    const float4 a = *(const float4*)(x + i);
    const float4 b = *(const float4*)(x + i + 4);
    const float4 ma = *(const float4*)(cmean + col);
    const float4 mb = *(const float4*)(cmean + col + 4);
    union { __hip_bfloat16 h[8]; uint4 u; } pk;
    pk.h[0] = __float2bfloat16(a.x - ma.x);
    pk.h[1] = __float2bfloat16(a.y - ma.y);
    pk.h[2] = __float2bfloat16(a.z - ma.z);
    pk.h[3] = __float2bfloat16(a.w - ma.w);
    pk.h[4] = __float2bfloat16(b.x - mb.x);
    pk.h[5] = __float2bfloat16(b.y - mb.y);
    pk.h[6] = __float2bfloat16(b.z - mb.z);
    pk.h[7] = __float2bfloat16(b.w - mb.w);
    *(uint4*)(xb + i) = pk.u;
    return;
  }
  const int b2 = blk - 16384;
  const float* src;
  __hip_bfloat16* dst;
  long base;
  if (b2 < 4096) {
    src = W1; dst = W1b; base = b2;
  } else if (b2 < 4608) {
    src = W2; dst = W2b; base = b2 - 4096;
  } else {
    src = beta; dst = betab; base = b2 - 4608;
  }
  const long i = ((base << 8) + threadIdx.x) << 3;
  const float4 a = *(const float4*)(src + i);
  const float4 b = *(const float4*)(src + i + 4);
  union { __hip_bfloat16 h[8]; uint4 u; } pk;
  pk.h[0] = __float2bfloat16(a.x);
  pk.h[1] = __float2bfloat16(a.y);
  pk.h[2] = __float2bfloat16(a.z);
  pk.h[3] = __float2bfloat16(a.w);
  pk.h[4] = __float2bfloat16(b.x);
  pk.h[5] = __float2bfloat16(b.y);
  pk.h[6] = __float2bfloat16(b.z);
  pk.h[7] = __float2bfloat16(b.w);
  *(uint4*)(dst + i) = pk.u;
}

// ---------------------------------------------------------------------------
// 256x256 NT GEMM, A-ring in LDS + B DIRECT FROM GLOBAL (L2-resident panel).
// 8 waves (2M x 4N), per-wave 128x64 = acc[8][4]. BK=32.
//
// Rationale (R3 post-mortem): with both operands in LDS, per-tile LDS work
// (96KB frag reads @4x A / 2x B redundancy + 32KB DMA writes) ~= the MFMA
// window -> any scheduling imperfection serializes the two ~1200-cyc terms.
// B-panel per block = 256x4096 bf16 = 2MB, L2-resident per XCD (swizzle maps
// XCD=bx, all 32 blocks share the panel), so B-fragments are loaded straight
// to VGPRs (global_load_dwordx4, compiler-tracked vmcnt), double-buffered one
// tile ahead. LDS now carries A only: 4-slot ring, 16KB/slot, 64KB total.
// Per-tile LDS: 16KB write + 64KB read (~750 cyc) << 1242-cyc MFMA.
//
// Pipeline per tile t: STG_A(t+3) [2 gl2lds]; B-regs(t+1) [4 dwordx4];
// ds_read ag (A-hi, in-tile) + nf (A-lo, t+1); 32 MFMA; vmcnt(6); barrier.
// vmcnt(6) = STG_A(t+3) 2 + B(t+1) 4 in flight; everything older (incl.
// STG_A(t+2), needed by nf readers next tile) proven landed. Slot (t+3)&3 =
// (t-1)&3: last read (ag) was lgkm-drained before this wave's t-1 MFMAs, so
// rewrite after the barrier is safe (same argument as R3, verified passing).
//
// A LDS chunk swizzle (proven 0-conflict): chunk (row,kq) at phys
// row*4 + (kq ^ ((row>>1)&3)); inverse folded into gl2lds SOURCE index;
// read offset kos = (ko ^ ((fr>>1)&3))*8. B from global needs NO swizzle.
// ---------------------------------------------------------------------------
template <int EPI>
__global__ __launch_bounds__(512, 2) void gemm256_bg(
    const __hip_bfloat16* __restrict__ A, int lda,
    const __hip_bfloat16* __restrict__ Bm, int ldb,
    const float* __restrict__ bias, float* __restrict__ C0, int ldc, int Kd) {
  constexpr int SLOT = 8192;                // A elems per slot (16 KB)
  __shared__ __hip_bfloat16 lds[4 * SLOT];  // 64 KB

  const int t_ = threadIdx.x;
  const int lane = t_ & 63;
  const int wv = t_ >> 6;
  const int wr = wv >> 2;  // M half (0/1)
  const int wc = wv & 3;   // N quarter (0..3)
  const int fr = lane & 15;
  const int ko = lane >> 4;
  const int kos = (ko ^ ((fr >> 1) & 3)) * 8;

  // T1: XCD-aware bijective swizzle (nwg % 8 == 0 for all our grids)
  const int gx = gridDim.x;
  const int nwg = gx * gridDim.y;
  const int f = blockIdx.y * gx + blockIdx.x;
  const int w = (f & 7) * (nwg >> 3) + (f >> 3);
  const int bx = w % gx;
  const int by = w / gx;

  const long rowA = (long)by * 256;
  const long rowB = (long)bx * 256;

  // A staging source: 512 threads cover 512 chunks (rows 0..127, 4/row);
  // second gl2lds covers rows 128..255.
  const int ci = (wv << 6) + lane;
  const int srow = ci >> 2;
  const int skq = (ci & 3) ^ ((ci >> 3) & 3);
  const __hip_bfloat16* sA0 = A + (rowA + srow) * (long)lda + skq * 8;
  const __hip_bfloat16* sA1 = sA0 + 128L * lda;

  auto STG = [&](int s, int k0) {
    __hip_bfloat16* d = lds + s * SLOT + wv * 512;
    gl2lds16(sA0 + k0, d);
    gl2lds16(sA1 + k0, d + 4096);
  };

  // B fragment source (per lane): row = rowB + wc*64 + ni*16 + fr, 16B at
  // k = k0 + ko*8. Lanes (fr,ko) -> 16 rows x 64B contiguous = clean L2 hits.
  const __hip_bfloat16* pB = Bm + (rowB + wc * 64 + fr) * (long)ldb + ko * 8;
  const long bStep = 16L * ldb;

  f32x4_t acc[8][4];
  const f32x4_t zero = {0.f, 0.f, 0.f, 0.f};
#pragma unroll
  for (int a = 0; a < 8; ++a)
#pragma unroll
    for (int b = 0; b < 4; ++b) acc[a][b] = zero;

  const int NT = Kd >> 5;  // even, >= 4

  // Prologue: B(0) regs first, then A slots 0,1,2. vmcnt(2) -> B0,A0,A1
  // landed (A2 in flight). Then preload tile0 A-lo fragments.
  bf16x8_t cb[4], nb[4];
#pragma unroll
  for (int ni = 0; ni < 4; ++ni)
    cb[ni] = *(const bf16x8_t*)(pB + ni * bStep);
  STG(0, 0);
  STG(1, 32);
  STG(2, 64);
  asm volatile("s_waitcnt vmcnt(2)" ::: "memory");
  __builtin_amdgcn_s_barrier();
  __builtin_amdgcn_sched_barrier(0);

  bf16x8_t F0a[4], F1a[4];
#pragma unroll
  for (int mi = 0; mi < 4; ++mi)
    F0a[mi] = *(const bf16x8_t*)&lds[(wr * 128 + mi * 16 + fr) * 32 + kos];

  auto BODY = [&](int t, bf16x8_t(&cf)[4], bf16x8_t(&cbv)[4],
                  bf16x8_t(&nf)[4], bf16x8_t(&nbv)[4]) {
    const int st = (t & 3) * SLOT;
    const bool pfA = (t + 3) < NT;
    const bool pfB = (t + 1) < NT;
    if (pfA) STG((t + 3) & 3, (t + 3) * 32);
    if (pfB) {
      const int kk = (t + 1) * 32;
#pragma unroll
      for (int ni = 0; ni < 4; ++ni)
        nbv[ni] = *(const bf16x8_t*)(pB + ni * bStep + kk);
    }
    // in-tile A-hi fragments
    bf16x8_t ag[4];
#pragma unroll
    for (int mi = 0; mi < 4; ++mi)
      ag[mi] =
          *(const bf16x8_t*)&lds[st + (wr * 128 + 64 + mi * 16 + fr) * 32 +
                                 kos];
    // next-tile A-lo fragments (drain hides under MFMAs)
    if (pfB) {
      const int s1 = ((t + 1) & 3) * SLOT;
#pragma unroll
      for (int mi = 0; mi < 4; ++mi)
        nf[mi] =
            *(const bf16x8_t*)&lds[s1 + (wr * 128 + mi * 16 + fr) * 32 + kos];
    }
    __builtin_amdgcn_s_setprio(1);
#pragma unroll
    for (int mi = 0; mi < 4; ++mi)
#pragma unroll
      for (int ni = 0; ni < 4; ++ni)
        acc[mi][ni] = __builtin_amdgcn_mfma_f32_16x16x32_bf16(
            cf[mi], cbv[ni], acc[mi][ni], 0, 0, 0);
#pragma unroll
    for (int mi = 0; mi < 4; ++mi)
#pragma unroll
      for (int ni = 0; ni < 4; ++ni)
        acc[4 + mi][ni] = __builtin_amdgcn_mfma_f32_16x16x32_bf16(
            ag[mi], cbv[ni], acc[4 + mi][ni], 0, 0, 0);
    __builtin_amdgcn_s_setprio(0);
    if (pfB) {
      if (pfA)
        asm volatile("s_waitcnt vmcnt(6)" ::: "memory");
      else
        asm volatile("s_waitcnt vmcnt(4)" ::: "memory");  // only B in flight
      __builtin_amdgcn_s_barrier();
      __builtin_amdgcn_sched_barrier(0);
    }
  };

  for (int t = 0; t < NT; t += 2) {
    BODY(t, F0a, cb, F1a, nb);
    BODY(t + 1, F1a, nb, F0a, cb);
  }

  // Epilogue. C/D layout: col = lane&15, row = (lane>>4)*4 + reg.
  const long cRow0 = rowA + wr * 128;
  const int cCol0 = (int)rowB + wc * 64;
#pragma unroll
  for (int a = 0; a < 8; ++a) {
#pragma unroll
    for (int b = 0; b < 4; ++b) {
      f32x4_t v4 = acc[a][b];
      const int col = cCol0 + b * 16 + fr;
#pragma unroll
      for (int r = 0; r < 4; ++r) {
        const long row = cRow0 + a * 16 + ko * 4 + r;
        float val = v4[r];
        if constexpr (EPI == 0) {
          val += bias[col];
        } else {
          val = 1.f / (1.f + __expf(-val));
        }
        C0[row * (long)ldc + col] = val;
      }
    }
  }
}

// ---------------------------------------------------------------------------
// 128x128 pipelined-fragment ring GEMM, 8 waves (2M x 4N), per-wave 64x32 =
// acc[4][2], BK=32, 4-slot ring (64 KB). Fragments preloaded one tile ahead.
// EPI 1: fc2 (q0,q2,q3 f32 + qb bf16). EPI 2: sigmoid (decode).
// ---------------------------------------------------------------------------
template <int EPI>
__global__ __launch_bounds__(512, 4) void gemm128_ring(
    const __hip_bfloat16* __restrict__ A, int lda,
    const __hip_bfloat16* __restrict__ Bm, int ldb,
    const float* __restrict__ bias, float* __restrict__ C0, int ldc,
    float* __restrict__ C2, float* __restrict__ C3,
    __hip_bfloat16* __restrict__ Cb, int Kd) {
  constexpr int SLOT = 8192;  // elems: A 4096 + B 4096 (16 KB)
  __shared__ __hip_bfloat16 lds[4 * SLOT];  // 64 KB

  const int t_ = threadIdx.x;
  const int lane = t_ & 63;
  const int wv = t_ >> 6;
  const int wr = wv >> 2;  // M half (0/1): rows wr*64..+63
  const int wc = wv & 3;   // N quarter: cols wc*32..+31
  const int fr = lane & 15;
  const int ko = lane >> 4;
  const int kos = (ko ^ ((fr >> 1) & 3)) * 8;

  // T1 swizzle
  const int gx = gridDim.x;
  const int nwg = gx * gridDim.y;
  const int f = blockIdx.y * gx + blockIdx.x;
  const int w = (f & 7) * (nwg >> 3) + (f >> 3);
  const int bx = w % gx;
  const int by = w / gx;

  const long rowA = (long)by * 128;
  const long rowB = (long)bx * 128;

  const int ci = (wv << 6) + lane;
  const int srow = ci >> 2;
  const int skq = (ci & 3) ^ ((ci >> 3) & 3);
  const __hip_bfloat16* sA = A + (rowA + srow) * (long)lda + skq * 8;
  const __hip_bfloat16* sB = Bm + (rowB + srow) * (long)ldb + skq * 8;

  auto STG = [&](int s, int k0) {
    __hip_bfloat16* d = lds + s * SLOT + wv * 512;
    gl2lds16(sA + k0, d);
    gl2lds16(sB + k0, d + 4096);
  };

  f32x4_t acc[4][2];
  const f32x4_t zero = {0.f, 0.f, 0.f, 0.f};
#pragma unroll
  for (int a = 0; a < 4; ++a)
#pragma unroll
    for (int b = 0; b < 2; ++b) acc[a][b] = zero;

  const int NT = Kd >> 5;  // even, >= 4

  STG(0, 0);
  STG(1, 32);
  STG(2, 64);
  asm volatile("s_waitcnt vmcnt(2)" ::: "memory");
  __builtin_amdgcn_s_barrier();
  __builtin_amdgcn_sched_barrier(0);

  bf16x8_t F0a[4], F0b[2], F1a[4], F1b[2];
#pragma unroll
  for (int mi = 0; mi < 4; ++mi)
    F0a[mi] = *(const bf16x8_t*)&lds[(wr * 64 + mi * 16 + fr) * 32 + kos];
#pragma unroll
  for (int ni = 0; ni < 2; ++ni)
    F0b[ni] =
        *(const bf16x8_t*)&lds[4096 + (wc * 32 + ni * 16 + fr) * 32 + kos];

  auto BODY = [&](int t, bf16x8_t(&cf)[4], bf16x8_t(&cb)[2],
                  bf16x8_t(&nf)[4], bf16x8_t(&nb)[2]) {
    if (t + 3 < NT) STG((t + 3) & 3, (t + 3) * 32);
    if (t + 1 < NT) {
      const int s1 = ((t + 1) & 3) * SLOT;
#pragma unroll
      for (int mi = 0; mi < 4; ++mi)
        nf[mi] =
            *(const bf16x8_t*)&lds[s1 + (wr * 64 + mi * 16 + fr) * 32 + kos];
#pragma unroll
      for (int ni = 0; ni < 2; ++ni)
        nb[ni] = *(const bf16x8_t*)&lds[s1 + 4096 +
                                        (wc * 32 + ni * 16 + fr) * 32 + kos];
    }
    __builtin_amdgcn_s_setprio(1);
#pragma unroll
    for (int mi = 0; mi < 4; ++mi)
#pragma unroll
      for (int ni = 0; ni < 2; ++ni)
        acc[mi][ni] = __builtin_amdgcn_mfma_f32_16x16x32_bf16(
            cf[mi], cb[ni], acc[mi][ni], 0, 0, 0);
    __builtin_amdgcn_s_setprio(0);
    if (t + 1 < NT) {
      if (t + 3 < NT)
        asm volatile("s_waitcnt vmcnt(2)" ::: "memory");
      else
        asm volatile("s_waitcnt vmcnt(0)" ::: "memory");
      __builtin_amdgcn_s_barrier();
      __builtin_amdgcn_sched_barrier(0);
    }
  };

  for (int t = 0; t < NT; t += 2) {
    BODY(t, F0a, F0b, F1a, F1b);
    BODY(t + 1, F1a, F1b, F0a, F0b);
  }

  const long cRow0 = rowA + wr * 64;
  const int cCol0 = (int)rowB + wc * 32;
#pragma unroll
  for (int a = 0; a < 4; ++a) {
#pragma unroll
    for (int b = 0; b < 2; ++b) {
      f32x4_t v4 = acc[a][b];
      const int col = cCol0 + b * 16 + fr;
#pragma unroll
      for (int r = 0; r < 4; ++r) {
        const long row = cRow0 + a * 16 + ko * 4 + r;
        float val = v4[r];
        if constexpr (EPI == 1) {
          val += bias[col];
          C0[row * (long)ldc + col] = val;
          C2[row * (long)ldc + col] = val;
          C3[row * (long)ldc + col] = val;
          Cb[row * (long)ldc + col] = __float2bfloat16(val);
        } else {
          val = 1.f / (1.f + __expf(-val));
          C0[row * (long)ldc + col] = val;
        }
      }
    }
  }
}

// ---------------------------------------------------------------------------
// Row LayerNorm + ReLU over h [8192 x 2048] f32; writes bf16 h' IN PLACE
// (bf16 row stride 4096 elems). Fully vectorized: thread t owns cols
// [t*8, t*8+8) -> 2x float4 loads, 1x uint4 store (16B/lane, G13).
// ---------------------------------------------------------------------------
__global__ __launch_bounds__(256) void ln_relu_kernel(
    void* hptr, const float* __restrict__ ln_w, const float* __restrict__ ln_b) {
  const int H = H_DIM;
  float* h = (float*)hptr;
  __hip_bfloat16* hb = (__hip_bfloat16*)hptr;

  const long row = blockIdx.x;
  const int t = threadIdx.x;
  const int lane = t & 63;
  const int wv = t >> 6;
  const float* hr = h + row * H + t * 8;

  const float4 va = *(const float4*)hr;
  const float4 vb = *(const float4*)(hr + 4);
  float v[8] = {va.x, va.y, va.z, va.w, vb.x, vb.y, vb.z, vb.w};

  __shared__ float red[8];

  float s = 0.f;
#pragma unroll
  for (int i = 0; i < 8; ++i) s += v[i];
#pragma unroll
  for (int off = 32; off; off >>= 1) s += __shfl_down(s, off);
  if (lane == 0) red[wv] = s;
  __syncthreads();
  const float mu = (red[0] + red[1] + red[2] + red[3]) * (1.f / (float)H);

  float vs = 0.f;
#pragma unroll
  for (int i = 0; i < 8; ++i) {
    float d = v[i] - mu;
    vs += d * d;
  }
#pragma unroll
  for (int off = 32; off; off >>= 1) vs += __shfl_down(vs, off);
  if (lane == 0) red[4 + wv] = vs;
  __syncthreads();
  const float var = (red[4] + red[5] + red[6] + red[7]) * (1.f / (float)H);
  const float rs = rsqrtf(var + LN_EPS);

  const float4 wa = *(const float4*)(ln_w + t * 8);
  const float4 wb = *(const float4*)(ln_w + t * 8 + 4);
  const float4 ba = *(const float4*)(ln_b + t * 8);
  const float4 bb = *(const float4*)(ln_b + t * 8 + 4);
  const float wgt[8] = {wa.x, wa.y, wa.z, wa.w, wb.x, wb.y, wb.z, wb.w};
  const float bia[8] = {ba.x, ba.y, ba.z, ba.w, bb.x, bb.y, bb.z, bb.w};

  union { __hip_bfloat16 hh[8]; uint4 u; } pk;
#pragma unroll
  for (int i = 0; i < 8; ++i) {
    float y = (v[i] - mu) * rs * wgt[i] + bia[i];
    pk.hh[i] = __float2bfloat16(fmaxf(y, 0.f));
  }
  *(uint4*)(hb + row * (long)D_DIM + t * 8) = pk.u;
}

// ---------------------------------------------------------------------------
extern "C" void kernel_launch(void* const* d_in, const int* in_sizes, int n_in,
                              void* d_out, int out_size, void* d_ws,
                              size_t ws_size, hipStream_t stream) {
  const float* x = (const float*)d_in[0];     // [8192,4096]
  const float* beta = (const float*)d_in[1];  // [4096,512]
  const float* cmean = (const float*)d_in[2]; // [4096]
  const float* W1 = (const float*)d_in[3];    // [2048,4096]
  const float* b1 = (const float*)d_in[4];    // [2048]
  const float* ln_w = (const float*)d_in[5];  // [2048]
  const float* ln_b = (const float*)d_in[6];  // [2048]
  const float* W2 = (const float*)d_in[7];    // [512,2048]
  const float* b2 = (const float*)d_in[8];    // [512]

  float* out = (float*)d_out;
  float* q0 = out;                          // [8192,512]
  float* xr = out + (size_t)B_DIM * K_DIM;  // [8192,4096] — 134 MB region
  float* q2 = xr + (size_t)B_DIM * D_DIM;   // [8192,512]
  float* q3 = q2 + (size_t)B_DIM * K_DIM;   // [8192,512]

  // Scratch inside d_out's xr region (dead until final decode GEMM):
  //   xb: bf16(x - cmean) [8192,4096] = 64 MB at xr+0
  //   h : f32 fc1 output  [8192,2048] = 64 MB at xr + 16.78M floats
  __hip_bfloat16* xb = (__hip_bfloat16*)xr;
  float* h = xr + (size_t)B_DIM * D_DIM / 2;
  __hip_bfloat16* hb = (__hip_bfloat16*)h;  // ln_relu writes bf16 in place

  // ws: bf16 weights + q bf16 (30 MB total; ws proven >= 64 MB)
  __hip_bfloat16* W1b = (__hip_bfloat16*)d_ws;          // 2048*4096
  __hip_bfloat16* W2b = W1b + (size_t)H_DIM * D_DIM;    // 512*2048
  __hip_bfloat16* betab = W2b + (size_t)K_DIM * H_DIM;  // 4096*512
  __hip_bfloat16* qb = betab + (size_t)D_DIM * K_DIM;   // 8192*512

  dim3 blk(256, 1, 1);
  dim3 blk512(512, 1, 1);

  // Pre-convert to bf16 (memory-bound, ONE launch)
  hipLaunchKernelGGL(conv_all_kernel, dim3(16384 + 4096 + 512 + 1024), blk, 0,
                     stream, x, cmean, xb, W1, W2, beta, W1b, W2b, betab);

  // fc1: h = xb @ W1b^T + b1   [M=8192, N=2048, Kd=4096] — A-ring + B-global
  hipLaunchKernelGGL((gemm256_bg<0>), dim3(H_DIM / 256, B_DIM / 256), blk512,
                     0, stream, xb, D_DIM, W1b, D_DIM, b1, h, H_DIM, D_DIM);

  // LayerNorm + ReLU -> bf16 h' in place (row stride 4096)
  hipLaunchKernelGGL(ln_relu_kernel, dim3(B_DIM), blk, 0, stream, (void*)h,
                     ln_w, ln_b);

  // fc2: q = h' @ W2b^T + b2   [M=8192, N=512, Kd=2048] — 128^2 8-wave ring
  hipLaunchKernelGGL((gemm128_ring<1>), dim3(K_DIM / 128, B_DIM / 128),
                     blk512, 0, stream, hb, D_DIM, W2b, H_DIM, b2, q0, K_DIM,
                     q2, q3, qb, H_DIM);

  // decode: x_recon = sigmoid(qb @ betab^T)  [M=8192, N=4096, Kd=512]
  hipLaunchKernelGGL((gemm128_ring<2>), dim3(D_DIM / 128, B_DIM / 128),
                     blk512, 0, stream, qb, K_DIM, betab, K_DIM,
                     (const float*)nullptr, xr, D_DIM, (float*)nullptr,
                     (float*)nullptr, (__hip_bfloat16*)nullptr, K_DIM);
}

// Round 5
// 519.761 us; speedup vs baseline: 1.1355x; 1.1355x over previous
//
#include <hip/hip_runtime.h>
#include <hip/hip_bf16.h>
#include <cstddef>
#include <cstdint>

#define LN_EPS 1e-5f

// Problem dims (fixed by the reference)
#define B_DIM 8192
#define D_DIM 4096
#define H_DIM 2048
#define K_DIM 512

typedef __bf16 bf16x8_t __attribute__((ext_vector_type(8)));
typedef float f32x4_t __attribute__((ext_vector_type(4)));

// sched_group_barrier masks (LLVM SchedGroupMask)
#define SGB __builtin_amdgcn_sched_group_barrier
#define SG_MFMA 0x008
#define SG_VMEM 0x070
#define SG_DSRD 0x100

// ---------------------------------------------------------------------------
// async global->LDS, 16B per lane. LDS dest = wave-uniform base + lane*16.
// ---------------------------------------------------------------------------
__device__ __forceinline__ void gl2lds16(const __hip_bfloat16* g,
                                         __hip_bfloat16* l) {
  __builtin_amdgcn_global_load_lds(
      (const __attribute__((address_space(1))) uint32_t*)g,
      (__attribute__((address_space(3))) uint32_t*)l, 16, 0, 0);
}

// ---------------------------------------------------------------------------
// f32 -> bf16 pre-convert, ONE launch: x-cmean (16384 blks), W1 (4096),
// W2 (512), beta (1024). 2048 f32 per block.
// ---------------------------------------------------------------------------
__global__ __launch_bounds__(256) void conv_all_kernel(
    const float* __restrict__ x, const float* __restrict__ cmean,
    __hip_bfloat16* __restrict__ xb, const float* __restrict__ W1,
    const float* __restrict__ W2, const float* __restrict__ beta,
    __hip_bfloat16* __restrict__ W1b, __hip_bfloat16* __restrict__ W2b,
    __hip_bfloat16* __restrict__ betab) {
  const int blk = blockIdx.x;
  if (blk < 16384) {  // x - cmean
    const long i = (((long)blk << 8) + threadIdx.x) << 3;
    const int col = (int)(i & (D_DIM - 1));
    const float4 a = *(const float4*)(x + i);
    const float4 b = *(const float4*)(x + i + 4);
    const float4 ma = *(const float4*)(cmean + col);
    const float4 mb = *(const float4*)(cmean + col + 4);
    union { __hip_bfloat16 h[8]; uint4 u; } pk;
    pk.h[0] = __float2bfloat16(a.x - ma.x);
    pk.h[1] = __float2bfloat16(a.y - ma.y);
    pk.h[2] = __float2bfloat16(a.z - ma.z);
    pk.h[3] = __float2bfloat16(a.w - ma.w);
    pk.h[4] = __float2bfloat16(b.x - mb.x);
    pk.h[5] = __float2bfloat16(b.y - mb.y);
    pk.h[6] = __float2bfloat16(b.z - mb.z);
    pk.h[7] = __float2bfloat16(b.w - mb.w);
    *(uint4*)(xb + i) = pk.u;
    return;
  }
  const int b2 = blk - 16384;
  const float* src;
  __hip_bfloat16* dst;
  long base;
  if (b2 < 4096) {
    src = W1; dst = W1b; base = b2;
  } else if (b2 < 4608) {
    src = W2; dst = W2b; base = b2 - 4096;
  } else {
    src = beta; dst = betab; base = b2 - 4608;
  }
  const long i = ((base << 8) + threadIdx.x) << 3;
  const float4 a = *(const float4*)(src + i);
  const float4 b = *(const float4*)(src + i + 4);
  union { __hip_bfloat16 h[8]; uint4 u; } pk;
  pk.h[0] = __float2bfloat16(a.x);
  pk.h[1] = __float2bfloat16(a.y);
  pk.h[2] = __float2bfloat16(a.z);
  pk.h[3] = __float2bfloat16(a.w);
  pk.h[4] = __float2bfloat16(b.x);
  pk.h[5] = __float2bfloat16(b.y);
  pk.h[6] = __float2bfloat16(b.z);
  pk.h[7] = __float2bfloat16(b.w);
  *(uint4*)(dst + i) = pk.u;
}

// ---------------------------------------------------------------------------
// 256x256 pipelined-fragment ring GEMM (R3 structure + T19 issue-order pin).
// 8 waves (2M x 4N), per-wave 128x64 = acc[8][4]. BK=32, 4-slot ring (128KB),
// stage t+3 during t, boundary vmcnt(4). Fragments reg-double-buffered one
// tile ahead.
//
// R1-R3 post-mortem: all schedules measured ~2438 cyc/tile = MFMA(1242) +
// LDS(~1200) SERIALIZED. Theory: compiler sinks the next-tile prefetch
// ds_reads below the MFMA cluster (no in-block consumer + high reg pressure),
// recreating serial order. Fix: sched_group_barrier pin per main-loop tile:
// [VMEM x4 (gl2lds)] [DS_READ x12 (ag first)] [MFMA x32]. MFMAs depend only
// on last tile's regs -> start at barrier exit; 12 reads drain under them
// (ag gated by lgkmcnt(12) at MFMA #17). SGB needs branch-free blocks ->
// loop peeled: branch-free main body + branchy 4-tile tail.
// ---------------------------------------------------------------------------
template <int EPI>
__global__ __launch_bounds__(512, 2) void gemm256_ring(
    const __hip_bfloat16* __restrict__ A, int lda,
    const __hip_bfloat16* __restrict__ Bm, int ldb,
    const float* __restrict__ bias, float* __restrict__ C0, int ldc, int Kd) {
  constexpr int SLOT = 16384;  // elems: A 8192 + B 8192 (32 KB)
  __shared__ __hip_bfloat16 lds[4 * SLOT];  // 128 KB

  const int t_ = threadIdx.x;
  const int lane = t_ & 63;
  const int wv = t_ >> 6;
  const int wr = wv >> 2;  // M half (0/1)
  const int wc = wv & 3;   // N quarter (0..3)
  const int fr = lane & 15;
  const int ko = lane >> 4;
  const int kos = (ko ^ ((fr >> 1) & 3)) * 8;

  // T1: XCD-aware bijective swizzle (nwg % 8 == 0 for all our grids)
  const int gx = gridDim.x;
  const int nwg = gx * gridDim.y;
  const int f = blockIdx.y * gx + blockIdx.x;
  const int w = (f & 7) * (nwg >> 3) + (f >> 3);
  const int bx = w % gx;
  const int by = w / gx;

  const long rowA = (long)by * 256;
  const long rowB = (long)bx * 256;

  // Staging source: 512 threads cover 512 chunks (rows 0..127, 4 chunks/row);
  // second call covers rows 128..255 (chunk id +512 leaves kq bits intact).
  const int ci = (wv << 6) + lane;
  const int srow = ci >> 2;
  const int skq = (ci & 3) ^ ((ci >> 3) & 3);
  const __hip_bfloat16* sA0 = A + (rowA + srow) * (long)lda + skq * 8;
  const __hip_bfloat16* sA1 = sA0 + 128L * lda;
  const __hip_bfloat16* sB0 = Bm + (rowB + srow) * (long)ldb + skq * 8;
  const __hip_bfloat16* sB1 = sB0 + 128L * ldb;

  auto STG = [&](int s, int k0) {
    __hip_bfloat16* d = lds + s * SLOT + wv * 512;
    gl2lds16(sA0 + k0, d);
    gl2lds16(sA1 + k0, d + 4096);
    gl2lds16(sB0 + k0, d + 8192);
    gl2lds16(sB1 + k0, d + 12288);
  };

  f32x4_t acc[8][4];
  const f32x4_t zero = {0.f, 0.f, 0.f, 0.f};
#pragma unroll
  for (int a = 0; a < 8; ++a)
#pragma unroll
    for (int b = 0; b < 4; ++b) acc[a][b] = zero;

  const int NT = Kd >> 5;  // even, >= 8

  // Prologue: stage tiles 0,1,2. vmcnt(4): t0,t1 landed; t2 in flight.
  STG(0, 0);
  STG(1, 32);
  STG(2, 64);
  asm volatile("s_waitcnt vmcnt(4)" ::: "memory");
  __builtin_amdgcn_s_barrier();
  __builtin_amdgcn_sched_barrier(0);

  bf16x8_t F0a[4], F0b[4], F1a[4], F1b[4];
#pragma unroll
  for (int mi = 0; mi < 4; ++mi)
    F0a[mi] = *(const bf16x8_t*)&lds[(wr * 128 + mi * 16 + fr) * 32 + kos];
#pragma unroll
  for (int ni = 0; ni < 4; ++ni)
    F0b[ni] =
        *(const bf16x8_t*)&lds[8192 + (wc * 64 + ni * 16 + fr) * 32 + kos];

  // Branch-free main body (requires t+3 < NT): SGB-pinned issue order.
  auto BODY_MAIN = [&](int t, bf16x8_t(&cf)[4], bf16x8_t(&cb)[4],
                       bf16x8_t(&nf)[4], bf16x8_t(&nb)[4]) {
    const int st = (t & 3) * SLOT;
    const int s1 = ((t + 1) & 3) * SLOT;
    STG((t + 3) & 3, (t + 3) * 32);
    // ag FIRST (in-order DS return -> only lgkmcnt(12) gates MFMA #17)
    bf16x8_t ag[4];
#pragma unroll
    for (int mi = 0; mi < 4; ++mi)
      ag[mi] =
          *(const bf16x8_t*)&lds[st + (wr * 128 + 64 + mi * 16 + fr) * 32 +
                                 kos];
#pragma unroll
    for (int mi = 0; mi < 4; ++mi)
      nf[mi] =
          *(const bf16x8_t*)&lds[s1 + (wr * 128 + mi * 16 + fr) * 32 + kos];
#pragma unroll
    for (int ni = 0; ni < 4; ++ni)
      nb[ni] = *(const bf16x8_t*)&lds[s1 + 8192 +
                                      (wc * 64 + ni * 16 + fr) * 32 + kos];
    __builtin_amdgcn_s_setprio(1);
#pragma unroll
    for (int mi = 0; mi < 4; ++mi)
#pragma unroll
      for (int ni = 0; ni < 4; ++ni)
        acc[mi][ni] = __builtin_amdgcn_mfma_f32_16x16x32_bf16(
            cf[mi], cb[ni], acc[mi][ni], 0, 0, 0);
#pragma unroll
    for (int mi = 0; mi < 4; ++mi)
#pragma unroll
      for (int ni = 0; ni < 4; ++ni)
        acc[4 + mi][ni] = __builtin_amdgcn_mfma_f32_16x16x32_bf16(
            ag[mi], cb[ni], acc[4 + mi][ni], 0, 0, 0);
    __builtin_amdgcn_s_setprio(0);
    // T19 pin: loads first, reads second, MFMAs last in ISSUE order.
    SGB(SG_VMEM, 4, 0);
    SGB(SG_DSRD, 12, 0);
    SGB(SG_MFMA, 32, 0);
    asm volatile("s_waitcnt vmcnt(4)" ::: "memory");
    __builtin_amdgcn_s_barrier();
    __builtin_amdgcn_sched_barrier(0);
  };

  // Branchy tail body (R3-exact).
  auto BODY = [&](int t, bf16x8_t(&cf)[4], bf16x8_t(&cb)[4],
                  bf16x8_t(&nf)[4], bf16x8_t(&nb)[4]) {
    const int st = (t & 3) * SLOT;
    if (t + 3 < NT) STG((t + 3) & 3, (t + 3) * 32);
    bf16x8_t ag[4];
#pragma unroll
    for (int mi = 0; mi < 4; ++mi)
      ag[mi] =
          *(const bf16x8_t*)&lds[st + (wr * 128 + 64 + mi * 16 + fr) * 32 +
                                 kos];
    if (t + 1 < NT) {
      const int s1 = ((t + 1) & 3) * SLOT;
#pragma unroll
      for (int mi = 0; mi < 4; ++mi)
        nf[mi] =
            *(const bf16x8_t*)&lds[s1 + (wr * 128 + mi * 16 + fr) * 32 + kos];
#pragma unroll
      for (int ni = 0; ni < 4; ++ni)
        nb[ni] = *(const bf16x8_t*)&lds[s1 + 8192 +
                                        (wc * 64 + ni * 16 + fr) * 32 + kos];
    }
    __builtin_amdgcn_s_setprio(1);
#pragma unroll
    for (int mi = 0; mi < 4; ++mi)
#pragma unroll
      for (int ni = 0; ni < 4; ++ni)
        acc[mi][ni] = __builtin_amdgcn_mfma_f32_16x16x32_bf16(
            cf[mi], cb[ni], acc[mi][ni], 0, 0, 0);
#pragma unroll
    for (int mi = 0; mi < 4; ++mi)
#pragma unroll
      for (int ni = 0; ni < 4; ++ni)
        acc[4 + mi][ni] = __builtin_amdgcn_mfma_f32_16x16x32_bf16(
            ag[mi], cb[ni], acc[4 + mi][ni], 0, 0, 0);
    __builtin_amdgcn_s_setprio(0);
    if (t + 1 < NT) {
      if (t + 3 < NT)
        asm volatile("s_waitcnt vmcnt(4)" ::: "memory");
      else
        asm volatile("s_waitcnt vmcnt(0)" ::: "memory");
      __builtin_amdgcn_s_barrier();
      __builtin_amdgcn_sched_barrier(0);
    }
  };

  int t = 0;
  for (; t + 4 < NT; t += 2) {  // last main pair stages up to t+4 <= NT-1
    BODY_MAIN(t, F0a, F0b, F1a, F1b);
    BODY_MAIN(t + 1, F1a, F1b, F0a, F0b);
  }
  for (; t < NT; t += 2) {
    BODY(t, F0a, F0b, F1a, F1b);
    BODY(t + 1, F1a, F1b, F0a, F0b);
  }

  // Epilogue. C/D layout: col = lane&15, row = (lane>>4)*4 + reg.
  const long cRow0 = rowA + wr * 128;
  const int cCol0 = (int)rowB + wc * 64;
#pragma unroll
  for (int a = 0; a < 8; ++a) {
#pragma unroll
    for (int b = 0; b < 4; ++b) {
      f32x4_t v4 = acc[a][b];
      const int col = cCol0 + b * 16 + fr;
#pragma unroll
      for (int r = 0; r < 4; ++r) {
        const long row = cRow0 + a * 16 + ko * 4 + r;
        float val = v4[r];
        if constexpr (EPI == 0) {
          val += bias[col];
        } else {
          val = 1.f / (1.f + __expf(-val));
        }
        C0[row * (long)ldc + col] = val;
      }
    }
  }
}

// ---------------------------------------------------------------------------
// 128x128 pipelined-fragment ring GEMM, 8 waves (2M x 4N), per-wave 64x32 =
// acc[4][2], BK=32, 4-slot ring (64 KB). Same T19 pin: [VMEM2][DS6][MFMA8]
// in the branch-free main loop. EPI 1: fc2 (q0,q2,q3 + qb). EPI 2: sigmoid.
// ---------------------------------------------------------------------------
template <int EPI>
__global__ __launch_bounds__(512, 4) void gemm128_ring(
    const __hip_bfloat16* __restrict__ A, int lda,
    const __hip_bfloat16* __restrict__ Bm, int ldb,
    const float* __restrict__ bias, float* __restrict__ C0, int ldc,
    float* __restrict__ C2, float* __restrict__ C3,
    __hip_bfloat16* __restrict__ Cb, int Kd) {
  constexpr int SLOT = 8192;  // elems: A 4096 + B 4096 (16 KB)
  __shared__ __hip_bfloat16 lds[4 * SLOT];  // 64 KB

  const int t_ = threadIdx.x;
  const int lane = t_ & 63;
  const int wv = t_ >> 6;
  const int wr = wv >> 2;  // M half (0/1): rows wr*64..+63
  const int wc = wv & 3;   // N quarter: cols wc*32..+31
  const int fr = lane & 15;
  const int ko = lane >> 4;
  const int kos = (ko ^ ((fr >> 1) & 3)) * 8;

  // T1 swizzle
  const int gx = gridDim.x;
  const int nwg = gx * gridDim.y;
  const int f = blockIdx.y * gx + blockIdx.x;
  const int w = (f & 7) * (nwg >> 3) + (f >> 3);
  const int bx = w % gx;
  const int by = w / gx;

  const long rowA = (long)by * 128;
  const long rowB = (long)bx * 128;

  const int ci = (wv << 6) + lane;
  const int srow = ci >> 2;
  const int skq = (ci & 3) ^ ((ci >> 3) & 3);
  const __hip_bfloat16* sA = A + (rowA + srow) * (long)lda + skq * 8;
  const __hip_bfloat16* sB = Bm + (rowB + srow) * (long)ldb + skq * 8;

  auto STG = [&](int s, int k0) {
    __hip_bfloat16* d = lds + s * SLOT + wv * 512;
    gl2lds16(sA + k0, d);
    gl2lds16(sB + k0, d + 4096);
  };

  f32x4_t acc[4][2];
  const f32x4_t zero = {0.f, 0.f, 0.f, 0.f};
#pragma unroll
  for (int a = 0; a < 4; ++a)
#pragma unroll
    for (int b = 0; b < 2; ++b) acc[a][b] = zero;

  const int NT = Kd >> 5;  // even, >= 8

  STG(0, 0);
  STG(1, 32);
  STG(2, 64);
  asm volatile("s_waitcnt vmcnt(2)" ::: "memory");
  __builtin_amdgcn_s_barrier();
  __builtin_amdgcn_sched_barrier(0);

  bf16x8_t F0a[4], F0b[2], F1a[4], F1b[2];
#pragma unroll
  for (int mi = 0; mi < 4; ++mi)
    F0a[mi] = *(const bf16x8_t*)&lds[(wr * 64 + mi * 16 + fr) * 32 + kos];
#pragma unroll
  for (int ni = 0; ni < 2; ++ni)
    F0b[ni] =
        *(const bf16x8_t*)&lds[4096 + (wc * 32 + ni * 16 + fr) * 32 + kos];

  auto BODY_MAIN = [&](int t, bf16x8_t(&cf)[4], bf16x8_t(&cb)[2],
                       bf16x8_t(&nf)[4], bf16x8_t(&nb)[2]) {
    const int s1 = ((t + 1) & 3) * SLOT;
    STG((t + 3) & 3, (t + 3) * 32);
#pragma unroll
    for (int mi = 0; mi < 4; ++mi)
      nf[mi] =
          *(const bf16x8_t*)&lds[s1 + (wr * 64 + mi * 16 + fr) * 32 + kos];
#pragma unroll
    for (int ni = 0; ni < 2; ++ni)
      nb[ni] = *(const bf16x8_t*)&lds[s1 + 4096 +
                                      (wc * 32 + ni * 16 + fr) * 32 + kos];
    __builtin_amdgcn_s_setprio(1);
#pragma unroll
    for (int mi = 0; mi < 4; ++mi)
#pragma unroll
      for (int ni = 0; ni < 2; ++ni)
        acc[mi][ni] = __builtin_amdgcn_mfma_f32_16x16x32_bf16(
            cf[mi], cb[ni], acc[mi][ni], 0, 0, 0);
    __builtin_amdgcn_s_setprio(0);
    SGB(SG_VMEM, 2, 0);
    SGB(SG_DSRD, 6, 0);
    SGB(SG_MFMA, 8, 0);
    asm volatile("s_waitcnt vmcnt(2)" ::: "memory");
    __builtin_amdgcn_s_barrier();
    __builtin_amdgcn_sched_barrier(0);
  };

  auto BODY = [&](int t, bf16x8_t(&cf)[4], bf16x8_t(&cb)[2],
                  bf16x8_t(&nf)[4], bf16x8_t(&nb)[2]) {
    if (t + 3 < NT) STG((t + 3) & 3, (t + 3) * 32);
    if (t + 1 < NT) {
      const int s1 = ((t + 1) & 3) * SLOT;
#pragma unroll
      for (int mi = 0; mi < 4; ++mi)
        nf[mi] =
            *(const bf16x8_t*)&lds[s1 + (wr * 64 + mi * 16 + fr) * 32 + kos];
#pragma unroll
      for (int ni = 0; ni < 2; ++ni)
        nb[ni] = *(const bf16x8_t*)&lds[s1 + 4096 +
                                        (wc * 32 + ni * 16 + fr) * 32 + kos];
    }
    __builtin_amdgcn_s_setprio(1);
#pragma unroll
    for (int mi = 0; mi < 4; ++mi)
#pragma unroll
      for (int ni = 0; ni < 2; ++ni)
        acc[mi][ni] = __builtin_amdgcn_mfma_f32_16x16x32_bf16(
            cf[mi], cb[ni], acc[mi][ni], 0, 0, 0);
    __builtin_amdgcn_s_setprio(0);
    if (t + 1 < NT) {
      if (t + 3 < NT)
        asm volatile("s_waitcnt vmcnt(2)" ::: "memory");
      else
        asm volatile("s_waitcnt vmcnt(0)" ::: "memory");
      __builtin_amdgcn_s_barrier();
      __builtin_amdgcn_sched_barrier(0);
    }
  };

  int t = 0;
  for (; t + 4 < NT; t += 2) {
    BODY_MAIN(t, F0a, F0b, F1a, F1b);
    BODY_MAIN(t + 1, F1a, F1b, F0a, F0b);
  }
  for (; t < NT; t += 2) {
    BODY(t, F0a, F0b, F1a, F1b);
    BODY(t + 1, F1a, F1b, F0a, F0b);
  }

  const long cRow0 = rowA + wr * 64;
  const int cCol0 = (int)rowB + wc * 32;
#pragma unroll
  for (int a = 0; a < 4; ++a) {
#pragma unroll
    for (int b = 0; b < 2; ++b) {
      f32x4_t v4 = acc[a][b];
      const int col = cCol0 + b * 16 + fr;
#pragma unroll
      for (int r = 0; r < 4; ++r) {
        const long row = cRow0 + a * 16 + ko * 4 + r;
        float val = v4[r];
        if constexpr (EPI == 1) {
          val += bias[col];
          C0[row * (long)ldc + col] = val;
          C2[row * (long)ldc + col] = val;
          C3[row * (long)ldc + col] = val;
          Cb[row * (long)ldc + col] = __float2bfloat16(val);
        } else {
          val = 1.f / (1.f + __expf(-val));
          C0[row * (long)ldc + col] = val;
        }
      }
    }
  }
}

// ---------------------------------------------------------------------------
// Row LayerNorm + ReLU over h [8192 x 2048] f32; writes bf16 h' IN PLACE
// (bf16 row stride 4096 elems). Vectorized: thread t owns cols [t*8, t*8+8)
// -> 2x float4 loads, 1x uint4 store (16B/lane, G13).
// ---------------------------------------------------------------------------
__global__ __launch_bounds__(256) void ln_relu_kernel(
    void* hptr, const float* __restrict__ ln_w, const float* __restrict__ ln_b) {
  const int H = H_DIM;
  float* h = (float*)hptr;
  __hip_bfloat16* hb = (__hip_bfloat16*)hptr;

  const long row = blockIdx.x;
  const int t = threadIdx.x;
  const int lane = t & 63;
  const int wv = t >> 6;
  const float* hr = h + row * H + t * 8;

  const float4 va = *(const float4*)hr;
  const float4 vb = *(const float4*)(hr + 4);
  float v[8] = {va.x, va.y, va.z, va.w, vb.x, vb.y, vb.z, vb.w};

  __shared__ float red[8];

  float s = 0.f;
#pragma unroll
  for (int i = 0; i < 8; ++i) s += v[i];
#pragma unroll
  for (int off = 32; off; off >>= 1) s += __shfl_down(s, off);
  if (lane == 0) red[wv] = s;
  __syncthreads();
  const float mu = (red[0] + red[1] + red[2] + red[3]) * (1.f / (float)H);

  float vs = 0.f;
#pragma unroll
  for (int i = 0; i < 8; ++i) {
    float d = v[i] - mu;
    vs += d * d;
  }
#pragma unroll
  for (int off = 32; off; off >>= 1) vs += __shfl_down(vs, off);
  if (lane == 0) red[4 + wv] = vs;
  __syncthreads();
  const float var = (red[4] + red[5] + red[6] + red[7]) * (1.f / (float)H);
  const float rs = rsqrtf(var + LN_EPS);

  const float4 wa = *(const float4*)(ln_w + t * 8);
  const float4 wb = *(const float4*)(ln_w + t * 8 + 4);
  const float4 ba = *(const float4*)(ln_b + t * 8);
  const float4 bb = *(const float4*)(ln_b + t * 8 + 4);
  const float wgt[8] = {wa.x, wa.y, wa.z, wa.w, wb.x, wb.y, wb.z, wb.w};
  const float bia[8] = {ba.x, ba.y, ba.z, ba.w, bb.x, bb.y, bb.z, bb.w};

  union { __hip_bfloat16 hh[8]; uint4 u; } pk;
#pragma unroll
  for (int i = 0; i < 8; ++i) {
    float y = (v[i] - mu) * rs * wgt[i] + bia[i];
    pk.hh[i] = __float2bfloat16(fmaxf(y, 0.f));
  }
  *(uint4*)(hb + row * (long)D_DIM + t * 8) = pk.u;
}

// ---------------------------------------------------------------------------
extern "C" void kernel_launch(void* const* d_in, const int* in_sizes, int n_in,
                              void* d_out, int out_size, void* d_ws,
                              size_t ws_size, hipStream_t stream) {
  const float* x = (const float*)d_in[0];     // [8192,4096]
  const float* beta = (const float*)d_in[1];  // [4096,512]
  const float* cmean = (const float*)d_in[2]; // [4096]
  const float* W1 = (const float*)d_in[3];    // [2048,4096]
  const float* b1 = (const float*)d_in[4];    // [2048]
  const float* ln_w = (const float*)d_in[5];  // [2048]
  const float* ln_b = (const float*)d_in[6];  // [2048]
  const float* W2 = (const float*)d_in[7];    // [512,2048]
  const float* b2 = (const float*)d_in[8];    // [512]

  float* out = (float*)d_out;
  float* q0 = out;                          // [8192,512]
  float* xr = out + (size_t)B_DIM * K_DIM;  // [8192,4096] — 134 MB region
  float* q2 = xr + (size_t)B_DIM * D_DIM;   // [8192,512]
  float* q3 = q2 + (size_t)B_DIM * K_DIM;   // [8192,512]

  // Scratch inside d_out's xr region (dead until final decode GEMM):
  //   xb: bf16(x - cmean) [8192,4096] = 64 MB at xr+0
  //   h : f32 fc1 output  [8192,2048] = 64 MB at xr + 16.78M floats
  __hip_bfloat16* xb = (__hip_bfloat16*)xr;
  float* h = xr + (size_t)B_DIM * D_DIM / 2;
  __hip_bfloat16* hb = (__hip_bfloat16*)h;  // ln_relu writes bf16 in place

  // ws: bf16 weights + q bf16 (30 MB total; ws proven >= 64 MB)
  __hip_bfloat16* W1b = (__hip_bfloat16*)d_ws;          // 2048*4096
  __hip_bfloat16* W2b = W1b + (size_t)H_DIM * D_DIM;    // 512*2048
  __hip_bfloat16* betab = W2b + (size_t)K_DIM * H_DIM;  // 4096*512
  __hip_bfloat16* qb = betab + (size_t)D_DIM * K_DIM;   // 8192*512

  dim3 blk(256, 1, 1);
  dim3 blk512(512, 1, 1);

  // Pre-convert to bf16 (memory-bound, ONE launch)
  hipLaunchKernelGGL(conv_all_kernel, dim3(16384 + 4096 + 512 + 1024), blk, 0,
                     stream, x, cmean, xb, W1, W2, beta, W1b, W2b, betab);

  // fc1: h = xb @ W1b^T + b1   [M=8192, N=2048, Kd=4096] — 256^2 ring + SGB
  hipLaunchKernelGGL((gemm256_ring<0>), dim3(H_DIM / 256, B_DIM / 256),
                     blk512, 0, stream, xb, D_DIM, W1b, D_DIM, b1, h, H_DIM,
                     D_DIM);

  // LayerNorm + ReLU -> bf16 h' in place (row stride 4096)
  hipLaunchKernelGGL(ln_relu_kernel, dim3(B_DIM), blk, 0, stream, (void*)h,
                     ln_w, ln_b);

  // fc2: q = h' @ W2b^T + b2   [M=8192, N=512, Kd=2048] — 128^2 ring + SGB
  hipLaunchKernelGGL((gemm128_ring<1>), dim3(K_DIM / 128, B_DIM / 128),
                     blk512, 0, stream, hb, D_DIM, W2b, H_DIM, b2, q0, K_DIM,
                     q2, q3, qb, H_DIM);

  // decode: x_recon = sigmoid(qb @ betab^T)  [M=8192, N=4096, Kd=512]
  hipLaunchKernelGGL((gemm128_ring<2>), dim3(D_DIM / 128, B_DIM / 128),
                     blk512, 0, stream, qb, K_DIM, betab, K_DIM,
                     (const float*)nullptr, xr, D_DIM, (float*)nullptr,
                     (float*)nullptr, (__hip_bfloat16*)nullptr, K_DIM);
}